// Round 17
// baseline (1183.987 us; speedup 1.0000x reference)
//
#include <hip/hip_runtime.h>

#define N_NODES 100000
#define N_EDGES 3200000
#define F_IN    1433
#define HID     16
#define N_CLS   7
#define NWINT   48                                   // K windows of 32 (K padded to 1536)
#define NWIN    12                                   // windows per wave (4 waves)
#define GB1     (N_NODES / 16)                       // 6250 gemm tiles of 16 rows (exact)
#define EB      (N_EDGES / 4 / 256)                  // 3125 bucket-fill blocks
#define ROWBLKS ((N_NODES + 255) / 256)              // 391
#define NTOT    (N_NODES * F_IN)                     // 143,300,000 (< 2^31)
#define NPB     98                                   // nodes per bucket
#define NB      ((N_NODES + NPB - 1) / NPB)          // 1021 buckets
#define BCAP    4096                                 // edges/bucket; Poisson(3125)+17σ

typedef __attribute__((ext_vector_type(8))) short short8v;
typedef __attribute__((ext_vector_type(4))) float float4v;

__device__ __forceinline__ unsigned short f2bf(float f) {
    unsigned u = __float_as_uint(f);
    u += 0x7fffu + ((u >> 16) & 1u);                 // RNE
    return (unsigned short)(u >> 16);
}

// ---------------- prep: pre-swizzled bf16 W1 fragments ----------------
__global__ void prep_w1_kernel(const float* __restrict__ W1, short* __restrict__ w1f) {
    int w = blockIdx.x;
    int l = threadIdx.x;
    int col = l & 15;
    int kb = w * 32 + (l >> 4) * 8;
    short8v f;
#pragma unroll
    for (int i = 0; i < 8; ++i) {
        int k = kb + i;
        float v = (k < F_IN) ? W1[k * HID + col] : 0.f;
        f[i] = (short)f2bf(v);
    }
    *(short8v*)(w1f + ((size_t)w * 64 + l) * 8) = f;
}

// ---------------- bucket fill: edges -> 1021 buckets of 98 nodes ------------
// Append positions from per-bucket counters are consecutive -> temporally
// clustered writes share L2 lines -> write-amp ~1 (~26MB vs ELL's 200MB).
__global__ void bucket_fill_kernel(const int* __restrict__ src, const int* __restrict__ dst,
                                   int* __restrict__ bcnt, int2* __restrict__ bucket) {
    int i = blockIdx.x * 256 + threadIdx.x;
    if (i < N_EDGES / 4) {
        int4 s4 = ((const int4*)src)[i];
        int4 d4 = ((const int4*)dst)[i];
        int b, p;
        b = d4.x / NPB; p = atomicAdd(&bcnt[b], 1);
        if (p < BCAP) bucket[(size_t)b * BCAP + p] = make_int2(s4.x, d4.x);
        b = d4.y / NPB; p = atomicAdd(&bcnt[b], 1);
        if (p < BCAP) bucket[(size_t)b * BCAP + p] = make_int2(s4.y, d4.y);
        b = d4.z / NPB; p = atomicAdd(&bcnt[b], 1);
        if (p < BCAP) bucket[(size_t)b * BCAP + p] = make_int2(s4.z, d4.z);
        b = d4.w / NPB; p = atomicAdd(&bcnt[b], 1);
        if (p < BCAP) bucket[(size_t)b * BCAP + p] = make_int2(s4.w, d4.w);
    }
}

// ---------------- layer 1: t1 = x @ W1 (standalone, R16 gemm path) ----------
// Straight-line register staging (VGPR~120, launch_bounds essential per R10),
// coalesced: instr (wl,j) covers rows {2j,2j+1} x 32 cols = 2 dense 128B
// lines. Per-window wave-private LDS redistribute (in-order DS pipe) + MFMA.
__global__ __launch_bounds__(256) void gemm1_kernel(const float* __restrict__ x,
                                                    const short* __restrict__ w1f,
                                                    float* __restrict__ t1) {
    __shared__ short xs[4][16][40];        // per-wave staging, 80B row stride
    __shared__ float red[4][256];
    const int tid = threadIdx.x;
    const int s = tid >> 6;                // wave / K-slice
    const int l = tid & 63;                // lane
    const int R0 = blockIdx.x * 16;
    const int g = l >> 4;                  // k-group
    const int c = l & 15;                  // A row / B col
    const int half = l >> 5;               // loader: row parity
    const int col = l & 31;                // loader: col within window
    const short* __restrict__ wfp = w1f + ((size_t)(s * NWIN) * 64 + l) * 8;

    float v[NWIN][8];
    if (blockIdx.x != GB1 - 1) {           // fast arm: unguarded
#pragma unroll
        for (int wl = 0; wl < NWIN; ++wl) {
            int kw = (s * NWIN + wl) * 32;
#pragma unroll
            for (int j = 0; j < 8; ++j)
                v[wl][j] = x[(size_t)((R0 + 2 * j + half) * F_IN + kw + col)];
        }
    } else {                               // final tile: clamp flat index
#pragma unroll
        for (int wl = 0; wl < NWIN; ++wl) {
            int kw = (s * NWIN + wl) * 32;
#pragma unroll
            for (int j = 0; j < 8; ++j) {
                int gi = (R0 + 2 * j + half) * F_IN + kw + col;
                if (gi > NTOT - 1) gi = NTOT - 1;
                v[wl][j] = x[gi];
            }
        }
    }

    float4v acc = {0.f, 0.f, 0.f, 0.f};
#pragma unroll
    for (int wl = 0; wl < NWIN; ++wl) {
#pragma unroll
        for (int j = 0; j < 8; ++j)
            xs[s][2 * j + half][col] = (short)f2bf(v[wl][j]);
        short8v af = *(const short8v*)&xs[s][c][g * 8];
        short8v bfv = *(const short8v*)(wfp + (size_t)wl * 512);
        acc = __builtin_amdgcn_mfma_f32_16x16x32_bf16(af, bfv, acc, 0, 0, 0);
    }

#pragma unroll
    for (int j = 0; j < 4; ++j) red[s][l * 4 + j] = acc[j];
    __syncthreads();
    {
        int r = tid >> 4, cc = tid & 15;
        int idx = ((r >> 2) * 16 + cc) * 4 + (r & 3);
        float vv = red[0][idx] + red[1][idx] + red[2][idx] + red[3][idx];
        t1[(long)(R0 + r) * HID + cc] = vv;
    }
}

// ---------------- agg1: per-bucket LDS reduction ----------------
// Block b: zero hl[98][16] (25KB), stream bucket edges (16 lanes/edge: gather
// t1[src*16+f] = one 64B line, ds_add_f32 into hl[dst-base][f]), then write
// h = relu(hl + t1 + b1) coalesced. No global scatter at all.
__global__ __launch_bounds__(256) void agg1_kernel(const float* __restrict__ t1,
                                                   const int* __restrict__ bcnt,
                                                   const int2* __restrict__ bucket,
                                                   const float* __restrict__ b1,
                                                   float* __restrict__ h) {
    __shared__ float hl[NPB][16];
    const int b = blockIdx.x;
    const int t = threadIdx.x;
    for (int idx = t; idx < NPB * 16; idx += 256) ((float*)hl)[idx] = 0.f;
    __syncthreads();
    int ne = bcnt[b]; if (ne > BCAP) ne = BCAP;
    const int base = b * NPB;
    const int eslot = t >> 4, f = t & 15;
    const int2* __restrict__ bp = bucket + (size_t)b * BCAP;
    for (int e = eslot; e < ne; e += 16) {
        int2 ed = bp[e];
        float v = t1[(size_t)ed.x * 16 + f];
        atomicAdd(&hl[ed.y - base][f], v);
    }
    __syncthreads();
    for (int idx = t; idx < NPB * 16; idx += 256) {
        int ln = idx >> 4, ff = idx & 15;
        int node = base + ln;
        if (node < N_NODES) {
            float vv = hl[ln][ff] + t1[(size_t)node * 16 + ff] + b1[ff];
            h[(size_t)node * 16 + ff] = fmaxf(vv, 0.f);
        }
    }
}

// ---------------- layer 2 (t2 padded to stride 8) ----------------
__global__ void gemm2_kernel(const float* __restrict__ h, const float* __restrict__ W2,
                             float* __restrict__ t2p) {
    int node = blockIdx.x * blockDim.x + threadIdx.x;
    if (node >= N_NODES) return;
    const float4* hr = (const float4*)(h + (size_t)node * HID);
    float hv[HID];
    ((float4*)hv)[0] = hr[0];
    ((float4*)hv)[1] = hr[1];
    ((float4*)hv)[2] = hr[2];
    ((float4*)hv)[3] = hr[3];
    float o8[8];
#pragma unroll
    for (int cNum = 0; cNum < N_CLS; ++cNum) {
        float a = 0.f;
#pragma unroll
        for (int j = 0; j < HID; ++j) a = fmaf(hv[j], W2[j * N_CLS + cNum], a);
        o8[cNum] = a;
    }
    o8[7] = 0.f;
    float4* op = (float4*)(t2p + (size_t)node * 8);
    op[0] = ((float4*)o8)[0];
    op[1] = ((float4*)o8)[1];
}

// ---------------- agg2: per-bucket LDS reduction (8 lanes/edge) -------------
__global__ __launch_bounds__(256) void agg2_kernel(const float* __restrict__ t2p,
                                                   const int* __restrict__ bcnt,
                                                   const int2* __restrict__ bucket,
                                                   const float* __restrict__ b2,
                                                   float* __restrict__ out) {
    __shared__ float ol[NPB][8];
    const int b = blockIdx.x;
    const int t = threadIdx.x;
    for (int idx = t; idx < NPB * 8; idx += 256) ((float*)ol)[idx] = 0.f;
    __syncthreads();
    int ne = bcnt[b]; if (ne > BCAP) ne = BCAP;
    const int base = b * NPB;
    const int eslot = t >> 3, f = t & 7;
    const int2* __restrict__ bp = bucket + (size_t)b * BCAP;
    for (int e = eslot; e < ne; e += 32) {
        int2 ed = bp[e];
        float v = t2p[(size_t)ed.x * 8 + f];   // f==7 reads pad 0
        atomicAdd(&ol[ed.y - base][f], v);
    }
    __syncthreads();
    for (int idx = t; idx < NPB * 7; idx += 256) {
        int ln = idx / 7, c = idx - ln * 7;
        int node = base + ln;
        if (node < N_NODES)
            out[(size_t)node * 7 + c] = ol[ln][c] + t2p[(size_t)node * 8 + c] + b2[c];
    }
}

// ---------------- launch ----------------

extern "C" void kernel_launch(void* const* d_in, const int* in_sizes, int n_in,
                              void* d_out, int out_size, void* d_ws, size_t ws_size,
                              hipStream_t stream) {
    const float* x  = (const float*)d_in[0];
    const int*   ei = (const int*)d_in[1];
    const float* W1 = (const float*)d_in[2];
    const float* b1 = (const float*)d_in[3];
    const float* W2 = (const float*)d_in[4];
    const float* b2 = (const float*)d_in[5];
    const int* src = ei;
    const int* dst = ei + N_EDGES;
    float* out = (float*)d_out;

    char* w = (char*)d_ws;
    float* t1  = (float*)w;  w += (size_t)N_NODES * HID * sizeof(float);
    float* h   = (float*)w;  w += (size_t)N_NODES * HID * sizeof(float);
    float* t2p = (float*)w;  w += (size_t)N_NODES * 8 * sizeof(float);
    short* w1f = (short*)w;  w += (size_t)NWINT * 64 * 8 * sizeof(short);
    int* bcnt  = (int*)w;    w += (size_t)NB * sizeof(int) + 4;   // keep int2 aligned
    int2* bucket = (int2*)(((uintptr_t)w + 7) & ~(uintptr_t)7);

    hipMemsetAsync(bcnt, 0, (size_t)NB * sizeof(int), stream);
    prep_w1_kernel<<<NWINT, 64, 0, stream>>>(W1, w1f);
    bucket_fill_kernel<<<EB, 256, 0, stream>>>(src, dst, bcnt, bucket);
    gemm1_kernel<<<GB1, 256, 0, stream>>>(x, w1f, t1);
    agg1_kernel<<<NB, 256, 0, stream>>>(t1, bcnt, bucket, b1, h);
    gemm2_kernel<<<ROWBLKS, 256, 0, stream>>>(h, W2, t2p);
    agg2_kernel<<<NB, 256, 0, stream>>>(t2p, bcnt, bucket, b2, out);
}

// Round 18
// 476.642 us; speedup vs baseline: 2.4840x; 2.4840x over previous
//
#include <hip/hip_runtime.h>

#define N_NODES 100000
#define N_EDGES 3200000
#define F_IN    1433
#define HID     16
#define N_CLS   7
#define CAP     96                                   // ELL capacity (col-major planes)
#define NWINT   48                                   // K windows of 32 (K padded to 1536)
#define NWIN    12                                   // windows per wave (4 waves)
#define GB1     (N_NODES / 16)                       // 6250 gemm tiles
#define ROWBLKS ((N_NODES + 255) / 256)              // 391
#define XB_STRIDE 1440                               // padded bf16 row (2880B, 16B-aligned)
#define XB_TOTAL  ((size_t)N_NODES * XB_STRIDE)
#define NF4     (N_NODES * F_IN / 4)                 // 35,825,000 float4s (exact)
#define PBR     2048                                 // repack blocks (grid-stride)
#define NPP     12500                                // nodes per XCD partition (100k/8)
#define NQUAD   (N_EDGES / 4)                        // 800,000 quads
#define QBLK    (NQUAD / 256)                        // 3125 quad-chunks
#define NFILLB  (QBLK * 8)                           // 25,000 fill blocks (x8 partitions)

typedef __attribute__((ext_vector_type(8))) short short8v;
typedef __attribute__((ext_vector_type(4))) float float4v;

__device__ __forceinline__ unsigned short f2bf(float f) {
    unsigned u = __float_as_uint(f);
    u += 0x7fffu + ((u >> 16) & 1u);                 // RNE
    return (unsigned short)(u >> 16);
}

// ---------------- prep: pre-swizzled bf16 W1 fragments ----------------
__global__ void prep_w1_kernel(const float* __restrict__ W1, short* __restrict__ w1f) {
    int w = blockIdx.x;
    int l = threadIdx.x;
    int col = l & 15;
    int kb = w * 32 + (l >> 4) * 8;
    short8v f;
#pragma unroll
    for (int i = 0; i < 8; ++i) {
        int k = kb + i;
        float v = (k < F_IN) ? W1[k * HID + col] : 0.f;
        f[i] = (short)f2bf(v);
    }
    *(short8v*)(w1f + ((size_t)w * 64 + l) * 8) = f;
}

// ---------------- fat: x->bf16 repack (first) ++ XCD-partitioned fill (tail)
// Repack (R13-proven ~150us): read x FLAT as coalesced float4, scatter bf16
// into xb stride 1440. Fill: partition p = dst/12500 handled ONLY by blocks
// with bid%8==p (blockIdx->XCD is round-robin) -> counters (50KB) and active
// col-major ELL frontier stay in ONE XCD's L2 -> no cross-XCD line migration
// (the R8/R14/R16/R17 fill killer). Edge quads re-read 8x (L3-absorbed).

__global__ __launch_bounds__(256) void fatprep_kernel(const float* __restrict__ x,
                                                      short* __restrict__ xb,
                                                      const int* __restrict__ src,
                                                      const int* __restrict__ dst,
                                                      int* __restrict__ cur,
                                                      int* __restrict__ ell) {
    const int bid = blockIdx.x;
    if (bid < PBR) {
        // ---- repack path ----
        for (long i4 = (long)bid * 256 + threadIdx.x; i4 < NF4; i4 += (long)PBR * 256) {
            float4 v = ((const float4*)x)[i4];
            float fv[4] = {v.x, v.y, v.z, v.w};
            unsigned e0 = (unsigned)(i4 * 4);
#pragma unroll
            for (int j = 0; j < 4; ++j) {
                unsigned e = e0 + j;
                unsigned row = e / 1433u;             // magic-mul
                unsigned col = e - row * 1433u;
                xb[(size_t)row * XB_STRIDE + col] = (short)f2bf(fv[j]);
            }
        }
        for (int p = bid * 256 + threadIdx.x; p < N_NODES * 7; p += PBR * 256) {
            int row = p / 7;
            int col = 1433 + (p - row * 7);
            xb[(size_t)row * XB_STRIDE + col] = 0;
        }
        return;
    }
    // ---- XCD-partitioned ELL fill ----
    const int f = bid - PBR;
    const int p = bid & 7;                 // == XCD id (round-robin mapping)
    const int j = f >> 3;
    const int q = j * 256 + threadIdx.x;   // quad index (exact: 3125*256=800k)
    int4 s4 = ((const int4*)src)[q];
    int4 d4 = ((const int4*)dst)[q];
    int pos;
    if (d4.x / NPP == p) { pos = atomicAdd(&cur[d4.x], 1); if (pos < CAP) ell[(size_t)pos * N_NODES + d4.x] = s4.x; }
    if (d4.y / NPP == p) { pos = atomicAdd(&cur[d4.y], 1); if (pos < CAP) ell[(size_t)pos * N_NODES + d4.y] = s4.y; }
    if (d4.z / NPP == p) { pos = atomicAdd(&cur[d4.z], 1); if (pos < CAP) ell[(size_t)pos * N_NODES + d4.z] = s4.z; }
    if (d4.w / NPP == p) { pos = atomicAdd(&cur[d4.w], 1); if (pos < CAP) ell[(size_t)pos * N_NODES + d4.w] = s4.w; }
}

// ---------------- layer 1: t1 = xb @ W1, aligned dwordx4 MFMA (R13 verbatim)
// Lane (g,c) loads its 8-bf16 A-frag as ONE aligned dwordx4 from xb; all 12
// windows straight-line into registers (VGPR~128; launch_bounds essential).
__global__ __launch_bounds__(256) void gemm1_kernel(const short* __restrict__ xb,
                                                    const short* __restrict__ w1f,
                                                    float* __restrict__ t1) {
    __shared__ float red[4][256];
    const int tid = threadIdx.x;
    const int s = tid >> 6;                // wave / K-slice
    const int l = tid & 63;                // lane
    const int R0 = blockIdx.x * 16;
    const int g = l >> 4;                  // k-group
    const int c = l & 15;                  // A row / B col
    const int row = R0 + c;
    const size_t base = (size_t)row * XB_STRIDE + g * 8;
    const short* __restrict__ wfp = w1f + ((size_t)(s * NWIN) * 64 + l) * 8;

    short8v bf[NWIN];
#pragma unroll
    for (int wl = 0; wl < NWIN; ++wl)
        bf[wl] = *(const short8v*)(wfp + (size_t)wl * 512);

    short8v af[NWIN];
#pragma unroll
    for (int wl = 0; wl < NWIN; ++wl) {
        size_t off = base + (size_t)(s * NWIN + wl) * 32;
        if (off > XB_TOTAL - 8) off = XB_TOTAL - 8;   // last-row k>=1440 tail
        af[wl] = *(const short8v*)(xb + off);
    }

    float4v acc = {0.f, 0.f, 0.f, 0.f};
#pragma unroll
    for (int wl = 0; wl < NWIN; ++wl)
        acc = __builtin_amdgcn_mfma_f32_16x16x32_bf16(af[wl], bf[wl], acc, 0, 0, 0);

    // cross-wave K reduction (D map: col=l&15, row=4*(l>>4)+j — verified R6+)
#pragma unroll
    for (int j = 0; j < 4; ++j) red[s][l * 4 + j] = acc[j];
    __syncthreads();
    {
        int r = tid >> 4, cc = tid & 15;
        int idx = ((r >> 2) * 16 + cc) * 4 + (r & 3);
        float vv = red[0][idx] + red[1][idx] + red[2][idx] + red[3][idx];
        t1[(long)(R0 + r) * HID + cc] = vv;
    }
}

// h = relu(gather-sum(t1) + t1 + b1); 4 lanes/node; col-major ELL reads
__global__ void agg1_kernel(const float* __restrict__ t1, const int* __restrict__ cur,
                            const int* __restrict__ ell, const float* __restrict__ b1,
                            float* __restrict__ h) {
    int tid = blockIdx.x * blockDim.x + threadIdx.x;
    if (tid >= N_NODES * 4) return;
    int node = tid >> 2;
    int q = tid & 3;
    int d = cur[node]; if (d > CAP) d = CAP;
    float4 a = *(const float4*)(t1 + ((size_t)node * 16 + q * 4));
    float4 b = *(const float4*)(b1 + q * 4);
    a.x += b.x; a.y += b.y; a.z += b.z; a.w += b.w;
    for (int e = 0; e < d; ++e) {
        int s = ell[(size_t)e * N_NODES + node];
        float4 v = *(const float4*)(t1 + ((size_t)s * 16 + q * 4));
        a.x += v.x; a.y += v.y; a.z += v.z; a.w += v.w;
    }
    float4 r = {fmaxf(a.x, 0.f), fmaxf(a.y, 0.f), fmaxf(a.z, 0.f), fmaxf(a.w, 0.f)};
    *(float4*)(h + ((size_t)node * 16 + q * 4)) = r;
}

// ---------------- layer 2 (t2 padded to stride 8) ----------------
__global__ void gemm2_kernel(const float* __restrict__ h, const float* __restrict__ W2,
                             float* __restrict__ t2p) {
    int node = blockIdx.x * blockDim.x + threadIdx.x;
    if (node >= N_NODES) return;
    const float4* hr = (const float4*)(h + (size_t)node * HID);
    float hv[HID];
    ((float4*)hv)[0] = hr[0];
    ((float4*)hv)[1] = hr[1];
    ((float4*)hv)[2] = hr[2];
    ((float4*)hv)[3] = hr[3];
    float o8[8];
#pragma unroll
    for (int cNum = 0; cNum < N_CLS; ++cNum) {
        float a = 0.f;
#pragma unroll
        for (int j = 0; j < HID; ++j) a = fmaf(hv[j], W2[j * N_CLS + cNum], a);
        o8[cNum] = a;
    }
    o8[7] = 0.f;
    float4* op = (float4*)(t2p + (size_t)node * 8);
    op[0] = ((float4*)o8)[0];
    op[1] = ((float4*)o8)[1];
}

// out = gather-sum(t2) + t2 + b2; 2 lanes/node; col-major ELL reads
__global__ void agg2_kernel(const float* __restrict__ t2p, const int* __restrict__ cur,
                            const int* __restrict__ ell, const float* __restrict__ b2,
                            float* __restrict__ out) {
    int tid = blockIdx.x * blockDim.x + threadIdx.x;
    if (tid >= N_NODES * 2) return;
    int node = tid >> 1;
    int q = tid & 1;
    int d = cur[node]; if (d > CAP) d = CAP;
    float4 a = *(const float4*)(t2p + ((size_t)node * 8 + q * 4));
    if (q == 0) {
        a.x += b2[0]; a.y += b2[1]; a.z += b2[2]; a.w += b2[3];
    } else {
        a.x += b2[4]; a.y += b2[5]; a.z += b2[6];
    }
    for (int e = 0; e < d; ++e) {
        int s = ell[(size_t)e * N_NODES + node];
        float4 v = *(const float4*)(t2p + ((size_t)s * 8 + q * 4));
        a.x += v.x; a.y += v.y; a.z += v.z; a.w += v.w;
    }
    float* op = out + (size_t)node * 7 + q * 4;
    op[0] = a.x; op[1] = a.y; op[2] = a.z;
    if (q == 0) op[3] = a.w;
}

// ---------------- launch ----------------

extern "C" void kernel_launch(void* const* d_in, const int* in_sizes, int n_in,
                              void* d_out, int out_size, void* d_ws, size_t ws_size,
                              hipStream_t stream) {
    const float* x  = (const float*)d_in[0];
    const int*   ei = (const int*)d_in[1];
    const float* W1 = (const float*)d_in[2];
    const float* b1 = (const float*)d_in[3];
    const float* W2 = (const float*)d_in[4];
    const float* b2 = (const float*)d_in[5];
    const int* src = ei;
    const int* dst = ei + N_EDGES;
    float* out = (float*)d_out;

    char* w = (char*)d_ws;
    float* t1  = (float*)w;  w += (size_t)N_NODES * HID * sizeof(float);
    float* h   = (float*)w;  w += (size_t)N_NODES * HID * sizeof(float);
    float* t2p = (float*)w;  w += (size_t)N_NODES * 8 * sizeof(float);
    int* cur   = (int*)w;    w += (size_t)N_NODES * sizeof(int);
    short* w1f = (short*)w;  w += (size_t)NWINT * 64 * 8 * sizeof(short);
    short* xb  = (short*)w;  w += XB_TOTAL * sizeof(short) + 256;  // +slack (clamped reads)
    int* ell   = (int*)w;    w += (size_t)CAP * N_NODES * sizeof(int);

    hipMemsetAsync(cur, 0, (size_t)N_NODES * sizeof(int), stream);
    prep_w1_kernel<<<NWINT, 64, 0, stream>>>(W1, w1f);

    // repack (first) ++ XCD-partitioned ELL fill (tail)
    fatprep_kernel<<<PBR + NFILLB, 256, 0, stream>>>(x, xb, src, dst, cur, ell);

    gemm1_kernel<<<GB1, 256, 0, stream>>>(xb, w1f, t1);
    agg1_kernel<<<(N_NODES * 4 + 255) / 256, 256, 0, stream>>>(t1, cur, ell, b1, h);
    gemm2_kernel<<<ROWBLKS, 256, 0, stream>>>(h, W2, t2p);
    agg2_kernel<<<(N_NODES * 2 + 255) / 256, 256, 0, stream>>>(t2p, cur, ell, b2, out);
}